// Round 1
// baseline (1217.857 us; speedup 1.0000x reference)
//
#include <hip/hip_runtime.h>

#define NN     50000
#define NE     20000
#define NNZV   800000
#define FD     256
#define EPSV   1e-5f
#define MPAD   20032     // NE rounded up to 64 for GEMM tiling
#define E2N_ROWS 32

typedef __attribute__((ext_vector_type(8))) __bf16 bf16x8;
typedef __attribute__((ext_vector_type(4))) float f32x4;

// ---- CSR construction -------------------------------------------------------

__global__ void hg_hist(const int* __restrict__ nidx, const int* __restrict__ eidx,
                        const float* __restrict__ wedge,
                        int* __restrict__ cnt_e, int* __restrict__ cnt_n,
                        float* __restrict__ Dacc) {
  int i = blockIdx.x * 256 + threadIdx.x;
  if (i >= NNZV) return;
  int e = eidx[i];
  int n = nidx[i];
  atomicAdd(&cnt_e[e], 1);
  atomicAdd(&cnt_n[n], 1);
  atomicAdd(&Dacc[n], wedge[e]);
}

__global__ void hg_exscan(const int* __restrict__ cnt, int n, int* __restrict__ off) {
  __shared__ int lds[1024];
  int t = threadIdx.x;
  int chunk = (n + 1023) >> 10;
  long lo = (long)t * chunk;
  long hi = lo + chunk;
  if (lo > n) lo = n;
  if (hi > n) hi = n;
  int s = 0;
  for (long i = lo; i < hi; ++i) s += cnt[i];
  lds[t] = s;
  for (int d = 1; d < 1024; d <<= 1) {
    __syncthreads();
    int u = (t >= d) ? lds[t - d] : 0;
    int v = lds[t];
    __syncthreads();
    lds[t] = u + v;
  }
  __syncthreads();
  int run = (t == 0) ? 0 : lds[t - 1];
  for (long i = lo; i < hi; ++i) { off[i] = run; run += cnt[i]; }
  if (t == 1023) off[n] = lds[1023];
}

__global__ void hg_scatter(const int* __restrict__ nidx, const int* __restrict__ eidx,
                           const int* __restrict__ off_e, const int* __restrict__ off_n,
                           int* __restrict__ cur_e, int* __restrict__ cur_n,
                           int* __restrict__ mem_e, int* __restrict__ mem_n) {
  int i = blockIdx.x * 256 + threadIdx.x;
  if (i >= NNZV) return;
  int n = nidx[i];
  int e = eidx[i];
  int pe = atomicAdd(&cur_e[e], 1);
  mem_e[off_e[e] + pe] = n;
  int pn = atomicAdd(&cur_n[n], 1);
  mem_n[off_n[n] + pn] = e;
}

__global__ void hg_inv(const int* __restrict__ cnt_e, const float* __restrict__ Dacc,
                       float* __restrict__ Binv, float* __restrict__ Dinv) {
  int i = blockIdx.x * 256 + threadIdx.x;
  if (i < NE) Binv[i] = cnt_e[i] ? 1.0f / (float)cnt_e[i] : 0.0f;
  if (i < NN) {
    float d = Dacc[i];
    Dinv[i] = (d != 0.0f) ? 1.0f / d : 0.0f;
  }
}

// ---- weights to bf16, transposed (Wt[n][k] = W[k][n]) -----------------------

__global__ void hg_wconv(const float* __restrict__ W1, const float* __restrict__ W2,
                         __bf16* __restrict__ Wt1, __bf16* __restrict__ Wt2) {
  int id = blockIdx.x * 256 + threadIdx.x;  // 65536 total
  int n = id >> 8;
  int k = id & 255;
  Wt1[n * FD + k] = (__bf16)W1[k * FD + n];
  Wt2[n * FD + k] = (__bf16)W2[k * FD + n];
}

// ---- node -> edge aggregation: Ebf[e][c] = Binv[e] * sum_m X[mem][c] --------

__global__ void hg_agg_n2e(const float* __restrict__ X, const int* __restrict__ off_e,
                           const int* __restrict__ mem_e, const float* __restrict__ Binv,
                           __bf16* __restrict__ Ebf) {
  int e = blockIdx.x;
  int c = threadIdx.x;
  int lo = off_e[e], hi = off_e[e + 1];
  float acc = 0.0f;
  for (int m = lo; m < hi; ++m) {
    acc += X[(size_t)mem_e[m] * FD + c];
  }
  Ebf[(size_t)e * FD + c] = (__bf16)(acc * Binv[e]);
}

// ---- GEMM: C[M x 256] = A[M x 256] @ Bt^T, bf16 MFMA, f32 accum -------------
// A row-major [M][256] bf16 (padded to MPAD rows), Bt is [256 cols][256 k] bf16.

__global__ void hg_gemm(const __bf16* __restrict__ A, const __bf16* __restrict__ Bt,
                        float* __restrict__ C, int Mrows) {
  int tid = threadIdx.x;
  int w = tid >> 6;
  int l = tid & 63;
  int m0 = blockIdx.x * 64 + w * 16;
  int n0 = blockIdx.y * 16;
  int kbase = (l >> 4) * 8;
  const bf16x8* Ap = (const bf16x8*)(A + (size_t)(m0 + (l & 15)) * FD + kbase);
  const bf16x8* Bp = (const bf16x8*)(Bt + (size_t)(n0 + (l & 15)) * FD + kbase);
  f32x4 acc = {0.f, 0.f, 0.f, 0.f};
#pragma unroll
  for (int ks = 0; ks < 8; ++ks) {
    bf16x8 a = Ap[ks * 4];   // +32 bf16 per k-step
    bf16x8 b = Bp[ks * 4];
    acc = __builtin_amdgcn_mfma_f32_16x16x32_bf16(a, b, acc, 0, 0, 0);
  }
  int crow = m0 + (l >> 4) * 4;
  int ccol = n0 + (l & 15);
#pragma unroll
  for (int r = 0; r < 4; ++r) {
    int rr = crow + r;
    if (rr < Mrows) C[(size_t)rr * FD + ccol] = acc[r];
  }
}

// ---- edge -> node aggregation + bias + BN partial stats ---------------------

__global__ void hg_agg_e2n(const float* __restrict__ eW, const int* __restrict__ off_n,
                           const int* __restrict__ mem_n, const float* __restrict__ Dinv,
                           const float* __restrict__ bias,
                           float* __restrict__ Out, float* __restrict__ stats) {
  int c = threadIdx.x;
  float bc = bias[c];
  float s = 0.0f, s2 = 0.0f;
  int base = blockIdx.x * E2N_ROWS;
  for (int i = 0; i < E2N_ROWS; ++i) {
    int node = base + i;
    if (node >= NN) break;
    int lo = off_n[node], hi = off_n[node + 1];
    float acc = 0.0f;
    for (int m = lo; m < hi; ++m) {
      acc += eW[(size_t)mem_n[m] * FD + c];
    }
    float val = fmaf(acc, Dinv[node], bc);
    Out[(size_t)node * FD + c] = val;
    s += val;
    s2 = fmaf(val, val, s2);
  }
  atomicAdd(&stats[c], s);
  atomicAdd(&stats[FD + c], s2);
}

// ---- BN finalize + fused apply/ReLU -----------------------------------------

__global__ void hg_bn_finalize(const float* __restrict__ stats, const float* __restrict__ g,
                               const float* __restrict__ be,
                               float* __restrict__ scale, float* __restrict__ shift) {
  int c = threadIdx.x;
  float mu = stats[c] * (1.0f / NN);
  float var = stats[FD + c] * (1.0f / NN) - mu * mu;
  float sc = g[c] * rsqrtf(var + EPSV);
  scale[c] = sc;
  shift[c] = fmaf(-mu, sc, be[c]);
}

__global__ void hg_apply(const float* __restrict__ OutA, const float* __restrict__ scale,
                         const float* __restrict__ shift, float* __restrict__ H) {
  int idx = blockIdx.x * 256 + threadIdx.x;   // over NN*FD/4 float4s
  if (idx >= NN * FD / 4) return;
  float4 v = ((const float4*)OutA)[idx];
  int c = (idx & (FD / 4 - 1)) * 4;
  v.x = fmaxf(fmaf(v.x, scale[c + 0], shift[c + 0]), 0.0f);
  v.y = fmaxf(fmaf(v.y, scale[c + 1], shift[c + 1]), 0.0f);
  v.z = fmaxf(fmaf(v.z, scale[c + 2], shift[c + 2]), 0.0f);
  v.w = fmaxf(fmaf(v.w, scale[c + 3], shift[c + 3]), 0.0f);
  ((float4*)H)[idx] = v;
}

// ---- launch -----------------------------------------------------------------

extern "C" void kernel_launch(void* const* d_in, const int* in_sizes, int n_in,
                              void* d_out, int out_size, void* d_ws, size_t ws_size,
                              hipStream_t stream) {
  const float* x    = (const float*)d_in[0];
  const int*   hei  = (const int*)d_in[1];
  const int*   nidx = hei;               // hyperedge_index[0]
  const int*   eidx = hei + NNZV;        // hyperedge_index[1]
  const float* wedge = (const float*)d_in[2];
  const float* W1  = (const float*)d_in[3];
  const float* b1  = (const float*)d_in[4];
  const float* g1  = (const float*)d_in[5];
  const float* be1 = (const float*)d_in[6];
  const float* W2  = (const float*)d_in[7];
  const float* b2  = (const float*)d_in[8];
  const float* g2  = (const float*)d_in[9];
  const float* be2 = (const float*)d_in[10];
  float* out = (float*)d_out;

  char* base = (char*)d_ws;
  size_t cur = 0;
  auto alloc = [&](size_t bytes) -> void* {
    void* p = base + cur;
    cur += (bytes + 255) & ~(size_t)255;
    return p;
  };
  // zero-initialized group (single memset over the span)
  int*   cnt_e = (int*)alloc(NE * 4);
  int*   cnt_n = (int*)alloc(NN * 4);
  int*   cur_e = (int*)alloc(NE * 4);
  int*   cur_n = (int*)alloc(NN * 4);
  float* Dacc  = (float*)alloc(NN * 4);
  size_t zero_span = cur;
  // rest
  int*   off_e = (int*)alloc((NE + 1) * 4);
  int*   off_n = (int*)alloc((NN + 1) * 4);
  int*   mem_e = (int*)alloc((size_t)NNZV * 4);
  int*   mem_n = (int*)alloc((size_t)NNZV * 4);
  float* Dinv  = (float*)alloc(NN * 4);
  float* Binv  = (float*)alloc(NE * 4);
  __bf16* Wt1  = (__bf16*)alloc(FD * FD * 2);
  __bf16* Wt2  = (__bf16*)alloc(FD * FD * 2);
  __bf16* Ebf  = (__bf16*)alloc((size_t)MPAD * FD * 2);
  float* eW    = (float*)alloc((size_t)MPAD * FD * 4);
  float* OutA  = (float*)alloc((size_t)NN * FD * 4);
  float* stats = (float*)alloc(2 * FD * 4);
  float* scale = (float*)alloc(FD * 4);
  float* shift = (float*)alloc(FD * 4);
  if (cur > ws_size) return;  // workspace too small — fail loudly via validation

  hipMemsetAsync(base, 0, zero_span, stream);

  hg_hist<<<(NNZV + 255) / 256, 256, 0, stream>>>(nidx, eidx, wedge, cnt_e, cnt_n, Dacc);
  hg_exscan<<<1, 1024, 0, stream>>>(cnt_e, NE, off_e);
  hg_exscan<<<1, 1024, 0, stream>>>(cnt_n, NN, off_n);
  hg_scatter<<<(NNZV + 255) / 256, 256, 0, stream>>>(nidx, eidx, off_e, off_n,
                                                     cur_e, cur_n, mem_e, mem_n);
  hg_inv<<<(NN + 255) / 256, 256, 0, stream>>>(cnt_e, Dacc, Binv, Dinv);
  hg_wconv<<<FD, 256, 0, stream>>>(W1, W2, Wt1, Wt2);

  // ---- layer 1 (input x, output -> d_out as h1)
  hg_agg_n2e<<<NE, FD, 0, stream>>>(x, off_e, mem_e, Binv, Ebf);
  hg_gemm<<<dim3(MPAD / 64, FD / 16), 256, 0, stream>>>(Ebf, Wt1, eW, NE);
  hipMemsetAsync(stats, 0, 2 * FD * 4, stream);
  hg_agg_e2n<<<(NN + E2N_ROWS - 1) / E2N_ROWS, FD, 0, stream>>>(eW, off_n, mem_n,
                                                                Dinv, b1, OutA, stats);
  hg_bn_finalize<<<1, FD, 0, stream>>>(stats, g1, be1, scale, shift);
  hg_apply<<<(NN * FD / 4 + 255) / 256, 256, 0, stream>>>(OutA, scale, shift, out);

  // ---- layer 2 (input h1 = d_out, output -> d_out)
  hg_agg_n2e<<<NE, FD, 0, stream>>>(out, off_e, mem_e, Binv, Ebf);
  hg_gemm<<<dim3(MPAD / 64, FD / 16), 256, 0, stream>>>(Ebf, Wt2, eW, NE);
  hipMemsetAsync(stats, 0, 2 * FD * 4, stream);
  hg_agg_e2n<<<(NN + E2N_ROWS - 1) / E2N_ROWS, FD, 0, stream>>>(eW, off_n, mem_n,
                                                                Dinv, b2, OutA, stats);
  hg_bn_finalize<<<1, FD, 0, stream>>>(stats, g2, be2, scale, shift);
  hg_apply<<<(NN * FD / 4 + 255) / 256, 256, 0, stream>>>(OutA, scale, shift, out);
}